// Round 2
// baseline (208.759 us; speedup 1.0000x reference)
//
#include <hip/hip_runtime.h>
#include <math.h>

// QClassifier fused kernel.
// Math reductions vs reference:
//  - RZ(phi) phases are unit-modulus and commute (as common scalars) through all
//    later real RY 2x2 rotations -> they cannot affect |state|^2. Dropped.
//  - StatePrep normalization: RY is orthogonal, so probs_k = (V x)_k^2 / ||x||^2.
//    1/||x||^2 is folded into the first MLP layer (no sqrt needed).
//  - Z/ZZ expectation signs are Walsh functions: all 10 features are Walsh
//    coefficients of the prob vector -> one 16-point FWHT (64 adds) yields them.
//  - feats @ W1^T + b1 uses W1 transposed into LDS (uniform broadcast reads).

#define PAD 20  // floats per staged sample (16 + 4 pad) -> conflict-free ds_read_b128

__global__ __launch_bounds__(256) void qc_fused(
    const float* __restrict__ x, const float* __restrict__ uw,
    const float* __restrict__ w1, const float* __restrict__ b1,
    const float* __restrict__ w2, const float* __restrict__ b2,
    float* __restrict__ out, int batch)
{
    __shared__ float sX[256 * PAD];   // 20.0 KiB staged samples
    __shared__ float sW1t[160];       // sW1t[f*16 + j] = w1[j*10 + f]
    __shared__ float sB1[16];
    __shared__ float sW2[32];
    __shared__ float sB2[2];
    __shared__ float sCS[8];          // cos(th_q/2), sin(th_q/2)

    const int t = threadIdx.x;

    // ---- phase 1: params into LDS (every block; tiny, L2-broadcast reads) ----
    if (t < 4) {
        float th = 0.5f * uw[2 * t];  // u_weights[q][0]; phi column is irrelevant
        sCS[t]     = cosf(th);
        sCS[4 + t] = sinf(th);
    }
    if (t < 160) sW1t[t] = w1[(t & 15) * 10 + (t >> 4)];
    if (t < 16)  sB1[t] = b1[t];
    if (t < 32)  sW2[t] = w2[t];
    if (t < 2)   sB2[t] = b2[t];

    // ---- phase 2: coalesced stage of 256 samples into padded LDS ----
    const float4* xv4 = (const float4*)x;
    const long nv4 = (long)batch * 4;
    const long base4 = (long)blockIdx.x * 1024;
#pragma unroll
    for (int r2 = 0; r2 < 4; ++r2) {
        int f = t + 256 * r2;                 // float4 index within block tile
        long g = base4 + f;
        float4 v = (g < nv4) ? xv4[g] : make_float4(0.f, 0.f, 0.f, 0.f);
        ((float4*)(sX + (f >> 2) * PAD))[f & 3] = v;
    }
    __syncthreads();

    // ---- phase 3: per-thread sample compute ----
    const float* myx = sX + t * PAD;
    float y[16];
#pragma unroll
    for (int i = 0; i < 4; ++i) {
        float4 v = ((const float4*)myx)[i];
        y[4 * i + 0] = v.x; y[4 * i + 1] = v.y;
        y[4 * i + 2] = v.z; y[4 * i + 3] = v.w;
    }

    float ss = 0.f;
#pragma unroll
    for (int i = 0; i < 16; ++i) ss = fmaf(y[i], y[i], ss);
    const float rn = 1.0f / ss;  // 1/||x||^2

    // 4 rounds of RY 2x2 rotations; qubit q acts on bit (3-q) (wire0 = MSB)
#pragma unroll
    for (int q = 0; q < 4; ++q) {
        const float cq = sCS[q], sq = sCS[4 + q];
        const int st = 8 >> q;
#pragma unroll
        for (int i = 0; i < 16; ++i) {
            if ((i & st) == 0) {
                float a = y[i], b = y[i + st];
                y[i]      = fmaf(cq, a, -sq * b);
                y[i + st] = fmaf(sq, a,  cq * b);
            }
        }
    }

    // unnormalized probs, then in-place 16-pt FWHT (Walsh coefficients)
    float p[16];
#pragma unroll
    for (int i = 0; i < 16; ++i) p[i] = y[i] * y[i];
#pragma unroll
    for (int st = 1; st < 16; st <<= 1) {
#pragma unroll
        for (int i = 0; i < 16; ++i) {
            if ((i & st) == 0) {
                float a = p[i], b = p[i + st];
                p[i]      = a + b;
                p[i + st] = a - b;
            }
        }
    }

    // features: z0..z3 -> masks 8,4,2,1 ; zz(i<j) -> 12,10,9,6,5,3
    constexpr int bmap[10] = {8, 4, 2, 1, 12, 10, 9, 6, 5, 3};

    float tacc[16];
#pragma unroll
    for (int j = 0; j < 16; ++j) tacc[j] = 0.f;
#pragma unroll
    for (int f = 0; f < 10; ++f) {
        const float ff = p[bmap[f]];
        const float* col = sW1t + f * 16;  // wave-uniform -> broadcast ds_read_b128
#pragma unroll
        for (int j = 0; j < 16; ++j) tacc[j] = fmaf(col[j], ff, tacc[j]);
    }

    float o0 = sB2[0], o1 = sB2[1];
#pragma unroll
    for (int j = 0; j < 16; ++j) {
        float h = fmaf(tacc[j], rn, sB1[j]);   // fold 1/||x||^2 here
        h = fmaxf(h, 0.f);
        o0 = fmaf(sW2[j],      h, o0);
        o1 = fmaf(sW2[16 + j], h, o1);
    }

    const long sidx = (long)blockIdx.x * 256 + t;
    if (sidx < batch) ((float2*)out)[sidx] = make_float2(o0, o1);
}

extern "C" void kernel_launch(void* const* d_in, const int* in_sizes, int n_in,
                              void* d_out, int out_size, void* d_ws, size_t ws_size,
                              hipStream_t stream) {
    const float* x  = (const float*)d_in[0];
    const float* uw = (const float*)d_in[1];
    const float* w1 = (const float*)d_in[2];
    const float* b1 = (const float*)d_in[3];
    const float* w2 = (const float*)d_in[4];
    const float* b2 = (const float*)d_in[5];
    float* out = (float*)d_out;

    int batch = in_sizes[0] / 16;
    int blocks = (batch + 255) / 256;
    hipLaunchKernelGGL(qc_fused, dim3(blocks), dim3(256), 0, stream,
                       x, uw, w1, b1, w2, b2, out, batch);
}